// Round 1
// baseline (483.576 us; speedup 1.0000x reference)
//
#include <hip/hip_runtime.h>

#define P_NUM   16320
#define B_NUM   32
#define NCLS    21
#define TOPK    500
#define CONF_THR 0.01f
#define NMS_THR  0.45f
#define OBJ_THR  0.01f
#define NBUCKET 2048
#define CAND_CAP 1024
#define NTHREADS 512

typedef unsigned long long u64;
typedef unsigned int u32;

struct SMemA {
    u32 hist[NBUCKET];    // 8192 B
    int csum[NTHREADS];   // 2048 B
    u64 keys[CAND_CAP];   // 8192 B
};

struct SMem {
    union {
        SMemA a;
        u64 mask[TOPK][8];  // 32000 B  (phase-disjoint with SMemA)
    } u;
    float4 sbox[TOPK];      // 8000 B
    float  sscore[TOPK];    // 2000 B
    float  sarea[TOPK];     // 2000 B
    int    order[TOPK];     // 2000 B
    int    cand_count;
    int    bstar;
    int    n_emit;
};

__global__ void fill_zero(float4* __restrict__ out, int n4) {
    int i = blockIdx.x * blockDim.x + threadIdx.x;
    if (i < n4) out[i] = make_float4(0.f, 0.f, 0.f, 0.f);
}

__global__ __launch_bounds__(NTHREADS)
void refinedet_nms(const float* __restrict__ arm_loc,
                   const float* __restrict__ arm_conf,
                   const float* __restrict__ odm_loc,
                   const float* __restrict__ odm_conf,
                   const float* __restrict__ priors,
                   float* __restrict__ out) {
    __shared__ SMem sm;
    const int task = blockIdx.x;
    const int b = task / (NCLS - 1);
    const int c = task % (NCLS - 1) + 1;
    const int tid = threadIdx.x;

    const float* armc = arm_conf + (size_t)b * P_NUM * 2;
    const float* odmc = odm_conf + (size_t)b * P_NUM * NCLS;

    // ---- Phase 1: score histogram (bucket = floor(score * 2048)) ----
    for (int i = tid; i < NBUCKET; i += NTHREADS) sm.u.a.hist[i] = 0u;
    if (tid == 0) sm.cand_count = 0;
    __syncthreads();

    for (int p = tid; p < P_NUM; p += NTHREADS) {
        float obj = armc[p * 2 + 1];
        float sc = (obj > OBJ_THR) ? odmc[p * NCLS + c] : 0.0f;
        if (sc > CONF_THR) {
            int bk = (int)(sc * (float)NBUCKET);
            if (bk > NBUCKET - 1) bk = NBUCKET - 1;
            atomicAdd(&sm.u.a.hist[bk], 1u);
        }
    }
    __syncthreads();

    // ---- Phase 2: find threshold bucket b* (largest bk with cum(>=bk) >= 500) ----
    {
        int t = tid;
        int s = 0;
        #pragma unroll
        for (int q = 0; q < 4; ++q) s += (int)sm.u.a.hist[t * 4 + q];
        sm.u.a.csum[t] = s;
    }
    __syncthreads();
    if (tid == 0) {
        int cum = 0, bstar = 0;
        for (int t = NTHREADS - 1; t >= 0; --t) {
            int c4 = sm.u.a.csum[t];
            if (cum + c4 >= TOPK) {
                for (int bk = t * 4 + 3; bk >= t * 4; --bk) {
                    cum += (int)sm.u.a.hist[bk];
                    if (cum >= TOPK) { bstar = bk; break; }
                }
                break;
            }
            cum += c4;
        }
        sm.bstar = bstar;   // if total < 500, stays 0 -> gather all valid
    }
    __syncthreads();
    const int bstar = sm.bstar;

    // ---- Phase 3: gather candidates (score, index) as sortable u64 keys ----
    // key = score_bits << 32 | ~p  -> descending u64 sort == (score desc, p asc)
    for (int p = tid; p < P_NUM; p += NTHREADS) {
        float obj = armc[p * 2 + 1];
        float sc = (obj > OBJ_THR) ? odmc[p * NCLS + c] : 0.0f;
        if (sc > CONF_THR) {
            int bk = (int)(sc * (float)NBUCKET);
            if (bk > NBUCKET - 1) bk = NBUCKET - 1;
            if (bk >= bstar) {
                int pos = atomicAdd(&sm.cand_count, 1);
                if (pos < CAND_CAP) {
                    u64 key = ((u64)__float_as_uint(sc) << 32) | (u32)(~(u32)p);
                    sm.u.a.keys[pos] = key;
                }
            }
        }
    }
    __syncthreads();
    int M = sm.cand_count; if (M > CAND_CAP) M = CAND_CAP;
    for (int i = M + tid; i < CAND_CAP; i += NTHREADS) sm.u.a.keys[i] = 0ull;
    __syncthreads();

    // ---- Phase 4: bitonic sort 1024 keys, descending ----
    for (int k = 2; k <= CAND_CAP; k <<= 1) {
        for (int j = k >> 1; j > 0; j >>= 1) {
            for (int t = tid; t < CAND_CAP; t += NTHREADS) {
                int ixj = t ^ j;
                if (ixj > t) {
                    u64 a = sm.u.a.keys[t];
                    u64 bb = sm.u.a.keys[ixj];
                    bool desc = ((t & k) == 0);
                    if (desc ? (a < bb) : (a > bb)) {
                        sm.u.a.keys[t] = bb;
                        sm.u.a.keys[ixj] = a;
                    }
                }
            }
            __syncthreads();
        }
    }
    const int N = (M < TOPK) ? M : TOPK;

    // ---- Phase 5: decode boxes for the top-N (cascaded ARM->ODM decode) ----
    // Exact FP replication of reference: no FMA contraction, correctly-rounded exp.
    for (int i = tid; i < TOPK; i += NTHREADS) {
        if (i < N) {
            u64 key = sm.u.a.keys[i];
            float sc = __uint_as_float((u32)(key >> 32));
            int p = (int)(~(u32)(key & 0xFFFFFFFFull));
            float4 pr = ((const float4*)priors)[p];
            float4 al = ((const float4*)(arm_loc + (size_t)b * P_NUM * 4))[p];
            float4 ol = ((const float4*)(odm_loc + (size_t)b * P_NUM * 4))[p];
            // decode(arm_loc, priors)
            float cx = __fadd_rn(pr.x, __fmul_rn(__fmul_rn(al.x, 0.1f), pr.z));
            float cy = __fadd_rn(pr.y, __fmul_rn(__fmul_rn(al.y, 0.1f), pr.w));
            float w  = __fmul_rn(pr.z, (float)exp((double)__fmul_rn(al.z, 0.2f)));
            float h  = __fmul_rn(pr.w, (float)exp((double)__fmul_rn(al.w, 0.2f)));
            float mnx = __fsub_rn(cx, __fmul_rn(w, 0.5f));
            float mny = __fsub_rn(cy, __fmul_rn(h, 0.5f));
            float mxx = __fadd_rn(mnx, w);
            float mxy = __fadd_rn(mny, h);
            // center_size
            float dcx = __fmul_rn(__fadd_rn(mxx, mnx), 0.5f);
            float dcy = __fmul_rn(__fadd_rn(mxy, mny), 0.5f);
            float dw  = __fsub_rn(mxx, mnx);
            float dh  = __fsub_rn(mxy, mny);
            // decode(odm_loc, default)
            float cx2 = __fadd_rn(dcx, __fmul_rn(__fmul_rn(ol.x, 0.1f), dw));
            float cy2 = __fadd_rn(dcy, __fmul_rn(__fmul_rn(ol.y, 0.1f), dh));
            float w2  = __fmul_rn(dw, (float)exp((double)__fmul_rn(ol.z, 0.2f)));
            float h2  = __fmul_rn(dh, (float)exp((double)__fmul_rn(ol.w, 0.2f)));
            float x1 = __fsub_rn(cx2, __fmul_rn(w2, 0.5f));
            float y1 = __fsub_rn(cy2, __fmul_rn(h2, 0.5f));
            float x2 = __fadd_rn(x1, w2);
            float y2 = __fadd_rn(y1, h2);
            sm.sbox[i] = make_float4(x1, y1, x2, y2);
            sm.sscore[i] = sc;
            sm.sarea[i] = __fmul_rn(__fsub_rn(x2, x1), __fsub_rn(y2, y1));
        } else {
            sm.sbox[i] = make_float4(0.f, 0.f, 0.f, 0.f);
            sm.sscore[i] = 0.0f;
            sm.sarea[i] = 0.0f;
        }
    }
    __syncthreads();   // keys (union) dead from here; mask may be written

    // ---- Phase 6: 500x500 suppression bitmask matrix ----
    // mask[i] bit j set <=> selecting i suppresses j:
    //   iou = inter / ((area_j - inter) + area_i) > 0.45   (exact ref FP order)
    for (int i = tid; i < TOPK; i += NTHREADS) {
        float4 bi = sm.sbox[i];
        float ai = sm.sarea[i];
        u64 bits = 0ull;
        int w = 0;
        for (int j = 0; j < TOPK; ++j) {
            float4 bj = sm.sbox[j];
            float xx1 = fmaxf(bj.x, bi.x);
            float yy1 = fmaxf(bj.y, bi.y);
            float xx2 = fminf(bj.z, bi.z);
            float yy2 = fminf(bj.w, bi.w);
            float iw = fmaxf(__fsub_rn(xx2, xx1), 0.0f);
            float ih = fmaxf(__fsub_rn(yy2, yy1), 0.0f);
            float inter = __fmul_rn(iw, ih);
            float denom = __fadd_rn(__fsub_rn(sm.sarea[j], inter), ai);
            float iou = __fdiv_rn(inter, denom);   // 0/0 -> NaN -> no suppress
            if (iou > NMS_THR) bits |= (1ull << (j & 63));
            if ((j & 63) == 63) { sm.u.mask[i][w] = bits; bits = 0ull; ++w; }
        }
        sm.u.mask[i][w] = bits;   // final partial word (j = 448..499)
    }
    __syncthreads();

    // ---- Phase 7: serial greedy sweep over bitmasks (thread 0) ----
    if (tid == 0) {
        u64 cur[8];
        #pragma unroll
        for (int w = 0; w < 8; ++w) {
            int lo = w * 64;
            u64 m;
            if (N >= lo + 64)      m = ~0ull;
            else if (N <= lo)      m = 0ull;
            else                   m = (1ull << (N - lo)) - 1ull;
            cur[w] = m;
        }
        int cnt = 0;
        for (int i = 0; i < N; ++i) {
            if ((cur[i >> 6] >> (i & 63)) & 1ull) {
                sm.order[cnt++] = i;
                #pragma unroll
                for (int w = 0; w < 8; ++w) cur[w] &= ~sm.u.mask[i][w];
            }
        }
        sm.n_emit = cnt;
    }
    __syncthreads();

    // ---- Phase 8: write emitted rows (padding already zeroed) ----
    float* o = out + (size_t)(b * NCLS + c) * TOPK * 5;
    const int cnt = sm.n_emit;
    for (int k = tid; k < cnt; k += NTHREADS) {
        int i = sm.order[k];
        float4 bx = sm.sbox[i];
        o[k * 5 + 0] = sm.sscore[i];
        o[k * 5 + 1] = bx.x;
        o[k * 5 + 2] = bx.y;
        o[k * 5 + 3] = bx.z;
        o[k * 5 + 4] = bx.w;
    }
}

extern "C" void kernel_launch(void* const* d_in, const int* in_sizes, int n_in,
                              void* d_out, int out_size, void* d_ws, size_t ws_size,
                              hipStream_t stream) {
    const float* arm_loc  = (const float*)d_in[0];
    const float* arm_conf = (const float*)d_in[1];
    const float* odm_loc  = (const float*)d_in[2];
    const float* odm_conf = (const float*)d_in[3];
    const float* priors   = (const float*)d_in[4];
    float* out = (float*)d_out;

    int n4 = out_size / 4;   // 1,680,000 / 4 = 420,000
    fill_zero<<<(n4 + 255) / 256, 256, 0, stream>>>((float4*)out, n4);
    refinedet_nms<<<B_NUM * (NCLS - 1), NTHREADS, 0, stream>>>(
        arm_loc, arm_conf, odm_loc, odm_conf, priors, out);
}

// Round 2
// 351.469 us; speedup vs baseline: 1.3759x; 1.3759x over previous
//
#include <hip/hip_runtime.h>
#include <math.h>

#define P_NUM   16320
#define B_NUM   32
#define NCLS    21
#define TOPK    500
#define CONF_THR 0.01f
#define NMS_THR  0.45f
#define OBJ_THR  0.01f
#define NBUCKET 2048
#define CAND_CAP 1024
#define NTHREADS 512
#define CHUNK   256

typedef unsigned long long u64;
typedef unsigned int u32;

struct SMemA {
    u32 hist[NBUCKET];    // 8192 B
    int csum[NTHREADS];   // 2048 B
    u64 keys[CAND_CAP];   // 8192 B
};

struct SMem {
    union {
        SMemA a;
        u64 mask[TOPK][8];  // 32000 B  (phase-disjoint with SMemA)
    } u;
    float4 sbox[TOPK];      // 8000 B
    float  sscore[TOPK];    // 2000 B
    float  sarea[TOPK];     // 2000 B
    int    order[TOPK];     // 2000 B
    int    cand_count;
    int    bstar;
    int    n_emit;
};

// ---- zero the class-0 slabs (rest of output fully written by main kernel) ----
__global__ void zero_cls0(float* __restrict__ out) {
    float* o = out + (size_t)blockIdx.x * NCLS * TOPK * 5;
    for (int f = threadIdx.x; f < TOPK * 5; f += blockDim.x) o[f] = 0.0f;
}

// ---- mask + transpose odm_conf into per-task contiguous score arrays ----
// ws layout: ws[(b*20 + (c-1)) * P_NUM + p] = (arm_obj > th) ? odm_conf[b][p][c] : 0
__global__ __launch_bounds__(256)
void mask_transpose(const float* __restrict__ arm_conf,
                    const float* __restrict__ odm_conf,
                    float* __restrict__ ws) {
    __shared__ float tile[NCLS][CHUNK + 1];   // +1 pad: conflict-free transpose
    __shared__ float obj[CHUNK];
    const int blk = blockIdx.x;
    const int b = blk >> 6;                   // 64 chunks per image
    const int ch = blk & 63;
    const int p0 = ch * CHUNK;
    const int np = min(CHUNK, P_NUM - p0);    // 256, last chunk 192
    const int tid = threadIdx.x;

    const float* oc = odm_conf + ((size_t)b * P_NUM + p0) * NCLS;
    const float* ac = arm_conf + ((size_t)b * P_NUM + p0) * 2;
    const int count = np * NCLS;
    for (int i = tid; i < count; i += 256) {
        float v = oc[i];                      // fully coalesced
        int p = i / NCLS;
        int c = i - p * NCLS;
        tile[c][p] = v;                       // addr stride 257 across lanes
    }
    if (tid < np) obj[tid] = ac[tid * 2 + 1];
    __syncthreads();

    for (int c = 1; c < NCLS; ++c) {
        float* w = ws + ((size_t)(b * 20 + (c - 1))) * P_NUM + p0;
        for (int p = tid; p < np; p += 256)
            w[p] = (obj[p] > OBJ_THR) ? tile[c][p] : 0.0f;   // coalesced store
    }
}

template <bool PACKED>
__global__ __launch_bounds__(NTHREADS)
void refinedet_main(const float* __restrict__ arm_loc,
                    const float* __restrict__ arm_conf,
                    const float* __restrict__ odm_loc,
                    const float* __restrict__ odm_conf,
                    const float* __restrict__ priors,
                    const float* __restrict__ ws_scores,
                    float* __restrict__ out) {
    __shared__ SMem sm;
    const int task = blockIdx.x;
    const int b = task / (NCLS - 1);
    const int c = task % (NCLS - 1) + 1;
    const int tid = threadIdx.x;

    // ---- Phase 0: load my 32 scores into registers (single global pass) ----
    for (int i = tid; i < NBUCKET; i += NTHREADS) sm.u.a.hist[i] = 0u;
    if (tid == 0) sm.cand_count = 0;

    float s[32];
    if (PACKED) {
        const float4* sp = (const float4*)(ws_scores + (size_t)task * P_NUM);
        #pragma unroll
        for (int v = 0; v < 8; ++v) {
            int q = tid + 512 * v;            // 4080 float4s total
            float4 val = (q < 4080) ? sp[q] : make_float4(0.f, 0.f, 0.f, 0.f);
            s[4 * v + 0] = val.x; s[4 * v + 1] = val.y;
            s[4 * v + 2] = val.z; s[4 * v + 3] = val.w;
        }
    } else {
        const float* armc = arm_conf + (size_t)b * P_NUM * 2;
        const float* odmc = odm_conf + (size_t)b * P_NUM * NCLS;
        #pragma unroll 4
        for (int k = 0; k < 32; ++k) {
            int p = tid + 512 * k;
            float sc = 0.0f;
            if (p < P_NUM) {
                float o = armc[p * 2 + 1];
                sc = (o > OBJ_THR) ? odmc[p * NCLS + c] : 0.0f;
            }
            s[k] = sc;
        }
    }
    __syncthreads();

    // ---- Phase 1: histogram from registers ----
    #pragma unroll 4
    for (int k = 0; k < 32; ++k) {
        float sc = s[k];
        if (sc > CONF_THR) {
            int bk = (int)(sc * (float)NBUCKET);
            if (bk > NBUCKET - 1) bk = NBUCKET - 1;
            atomicAdd(&sm.u.a.hist[bk], 1u);
        }
    }
    __syncthreads();

    // ---- Phase 2: threshold bucket b* ----
    {
        int s4 = 0;
        #pragma unroll
        for (int q = 0; q < 4; ++q) s4 += (int)sm.u.a.hist[tid * 4 + q];
        sm.u.a.csum[tid] = s4;
    }
    __syncthreads();
    if (tid == 0) {
        int cum = 0, bstar = 0;
        for (int t = NTHREADS - 1; t >= 0; --t) {
            int c4 = sm.u.a.csum[t];
            if (cum + c4 >= TOPK) {
                for (int bk = t * 4 + 3; bk >= t * 4; --bk) {
                    cum += (int)sm.u.a.hist[bk];
                    if (cum >= TOPK) { bstar = bk; break; }
                }
                break;
            }
            cum += c4;
        }
        sm.bstar = bstar;
    }
    __syncthreads();
    const int bstar = sm.bstar;

    // ---- Phase 3: gather candidates from registers ----
    #pragma unroll 4
    for (int k = 0; k < 32; ++k) {
        float sc = s[k];
        if (sc > CONF_THR) {
            int bk = (int)(sc * (float)NBUCKET);
            if (bk > NBUCKET - 1) bk = NBUCKET - 1;
            if (bk >= bstar) {
                int p;
                if (PACKED) p = 4 * (tid + 512 * (k >> 2)) + (k & 3);
                else        p = tid + 512 * k;
                int pos = atomicAdd(&sm.cand_count, 1);
                if (pos < CAND_CAP) {
                    u64 key = ((u64)__float_as_uint(sc) << 32) | (u32)(~(u32)p);
                    sm.u.a.keys[pos] = key;
                }
            }
        }
    }
    __syncthreads();
    int M = sm.cand_count; if (M > CAND_CAP) M = CAND_CAP;
    for (int i = M + tid; i < CAND_CAP; i += NTHREADS) sm.u.a.keys[i] = 0ull;
    __syncthreads();

    // ---- Phase 4: bitonic sort 1024 keys, descending ----
    for (int k = 2; k <= CAND_CAP; k <<= 1) {
        for (int j = k >> 1; j > 0; j >>= 1) {
            for (int t = tid; t < CAND_CAP; t += NTHREADS) {
                int ixj = t ^ j;
                if (ixj > t) {
                    u64 a = sm.u.a.keys[t];
                    u64 bb = sm.u.a.keys[ixj];
                    bool desc = ((t & k) == 0);
                    if (desc ? (a < bb) : (a > bb)) {
                        sm.u.a.keys[t] = bb;
                        sm.u.a.keys[ixj] = a;
                    }
                }
            }
            __syncthreads();
        }
    }
    const int N = (M < TOPK) ? M : TOPK;

    // ---- Phase 5: cascaded decode for top-N (exact ref FP: no FMA, CR exp) ----
    for (int i = tid; i < TOPK; i += NTHREADS) {
        if (i < N) {
            u64 key = sm.u.a.keys[i];
            float sc = __uint_as_float((u32)(key >> 32));
            int p = (int)(~(u32)(key & 0xFFFFFFFFull));
            float4 pr = ((const float4*)priors)[p];
            float4 al = ((const float4*)(arm_loc + (size_t)b * P_NUM * 4))[p];
            float4 ol = ((const float4*)(odm_loc + (size_t)b * P_NUM * 4))[p];
            float cx = __fadd_rn(pr.x, __fmul_rn(__fmul_rn(al.x, 0.1f), pr.z));
            float cy = __fadd_rn(pr.y, __fmul_rn(__fmul_rn(al.y, 0.1f), pr.w));
            float w  = __fmul_rn(pr.z, (float)exp((double)__fmul_rn(al.z, 0.2f)));
            float h  = __fmul_rn(pr.w, (float)exp((double)__fmul_rn(al.w, 0.2f)));
            float mnx = __fsub_rn(cx, __fmul_rn(w, 0.5f));
            float mny = __fsub_rn(cy, __fmul_rn(h, 0.5f));
            float mxx = __fadd_rn(mnx, w);
            float mxy = __fadd_rn(mny, h);
            float dcx = __fmul_rn(__fadd_rn(mxx, mnx), 0.5f);
            float dcy = __fmul_rn(__fadd_rn(mxy, mny), 0.5f);
            float dw  = __fsub_rn(mxx, mnx);
            float dh  = __fsub_rn(mxy, mny);
            float cx2 = __fadd_rn(dcx, __fmul_rn(__fmul_rn(ol.x, 0.1f), dw));
            float cy2 = __fadd_rn(dcy, __fmul_rn(__fmul_rn(ol.y, 0.1f), dh));
            float w2  = __fmul_rn(dw, (float)exp((double)__fmul_rn(ol.z, 0.2f)));
            float h2  = __fmul_rn(dh, (float)exp((double)__fmul_rn(ol.w, 0.2f)));
            float x1 = __fsub_rn(cx2, __fmul_rn(w2, 0.5f));
            float y1 = __fsub_rn(cy2, __fmul_rn(h2, 0.5f));
            float x2 = __fadd_rn(x1, w2);
            float y2 = __fadd_rn(y1, h2);
            sm.sbox[i] = make_float4(x1, y1, x2, y2);
            sm.sscore[i] = sc;
            sm.sarea[i] = __fmul_rn(__fsub_rn(x2, x1), __fsub_rn(y2, y1));
        } else {
            sm.sbox[i] = make_float4(0.f, 0.f, 0.f, 0.f);
            sm.sscore[i] = 0.0f;
            sm.sarea[i] = 0.0f;
        }
    }
    __syncthreads();   // keys (union) dead; mask region live

    // ---- Phase 6: triangular suppression bitmask (j > i only) ----
    // mask[i] bit j set <=> i suppresses j (greedy only hits lower-scored j).
    // Balanced pairing: thread t handles rows t and 499-t (uniform trip count).
    {
        auto do_row = [&](int i) {
            float4 bi = sm.sbox[i];
            float ai = sm.sarea[i];
            #pragma unroll
            for (int w = 0; w < 8; ++w) {
                int jlo = max(i + 1, w * 64);
                int jhi = min(N, (w + 1) * 64);
                u64 bits = 0ull;
                for (int j = jlo; j < jhi; ++j) {
                    float4 bj = sm.sbox[j];
                    float xx1 = fmaxf(bj.x, bi.x);
                    float yy1 = fmaxf(bj.y, bi.y);
                    float xx2 = fminf(bj.z, bi.z);
                    float yy2 = fminf(bj.w, bi.w);
                    float iw = fmaxf(__fsub_rn(xx2, xx1), 0.0f);
                    float ih = fmaxf(__fsub_rn(yy2, yy1), 0.0f);
                    float inter = __fmul_rn(iw, ih);
                    float denom = __fadd_rn(__fsub_rn(sm.sarea[j], inter), ai);
                    float iou = __fdiv_rn(inter, denom);
                    if (iou > NMS_THR) bits |= (1ull << (j & 63));
                }
                sm.u.mask[i][w] = bits;
            }
        };
        if (tid < TOPK / 2) {
            int r0 = tid, r1 = TOPK - 1 - tid;
            if (r0 < N) do_row(r0);
            if (r1 < N) do_row(r1);
        }
    }
    __syncthreads();

    // ---- Phase 7: serial greedy sweep over bitmasks ----
    if (tid == 0) {
        u64 cur[8];
        #pragma unroll
        for (int w = 0; w < 8; ++w) {
            int lo = w * 64;
            u64 m;
            if (N >= lo + 64)      m = ~0ull;
            else if (N <= lo)      m = 0ull;
            else                   m = (1ull << (N - lo)) - 1ull;
            cur[w] = m;
        }
        int cnt = 0;
        for (int i = 0; i < N; ++i) {
            if ((cur[i >> 6] >> (i & 63)) & 1ull) {
                sm.order[cnt++] = i;
                #pragma unroll
                for (int w = 0; w < 8; ++w) cur[w] &= ~sm.u.mask[i][w];
            }
        }
        sm.n_emit = cnt;
    }
    __syncthreads();

    // ---- Phase 8: write full [500,5] slab (zeros beyond cnt) ----
    float* o = out + ((size_t)(b * NCLS + c)) * TOPK * 5;
    const int cnt = sm.n_emit;
    for (int f = tid; f < TOPK * 5; f += NTHREADS) {
        int k = f / 5;
        int r = f - k * 5;
        float val = 0.0f;
        if (k < cnt) {
            int i = sm.order[k];
            float4 bx = sm.sbox[i];
            val = (r == 0) ? sm.sscore[i]
                : (r == 1) ? bx.x
                : (r == 2) ? bx.y
                : (r == 3) ? bx.z
                :            bx.w;
        }
        o[f] = val;
    }
}

extern "C" void kernel_launch(void* const* d_in, const int* in_sizes, int n_in,
                              void* d_out, int out_size, void* d_ws, size_t ws_size,
                              hipStream_t stream) {
    const float* arm_loc  = (const float*)d_in[0];
    const float* arm_conf = (const float*)d_in[1];
    const float* odm_loc  = (const float*)d_in[2];
    const float* odm_conf = (const float*)d_in[3];
    const float* priors   = (const float*)d_in[4];
    float* out = (float*)d_out;

    zero_cls0<<<B_NUM, 256, 0, stream>>>(out);

    const size_t need = (size_t)B_NUM * (NCLS - 1) * P_NUM * sizeof(float); // 41.8 MB
    if (ws_size >= need) {
        float* wsf = (float*)d_ws;
        mask_transpose<<<B_NUM * 64, 256, 0, stream>>>(arm_conf, odm_conf, wsf);
        refinedet_main<true><<<B_NUM * (NCLS - 1), NTHREADS, 0, stream>>>(
            arm_loc, arm_conf, odm_loc, odm_conf, priors, wsf, out);
    } else {
        refinedet_main<false><<<B_NUM * (NCLS - 1), NTHREADS, 0, stream>>>(
            arm_loc, arm_conf, odm_loc, odm_conf, priors, nullptr, out);
    }
}

// Round 3
// 266.080 us; speedup vs baseline: 1.8174x; 1.3209x over previous
//
#include <hip/hip_runtime.h>
#include <math.h>

#define P_NUM   16320
#define B_NUM   32
#define NCLS    21
#define TOPK    500
#define CONF_THR 0.01f
#define NMS_THR  0.45f
#define OBJ_THR  0.01f
#define NBUCKET 2048
#define CAND_CAP 1024
#define NTHREADS 512
#define CHUNK   256
#define NTASK   (B_NUM * (NCLS - 1))

typedef unsigned long long u64;
typedef unsigned int u32;

struct SMemA {
    u32 hist[NBUCKET];    // 8192 B
    int csum[NTHREADS];   // 2048 B
    int gsum[64];         // 256 B
    u64 keys[CAND_CAP];   // 8192 B
};

struct SMem {
    union {
        SMemA a;
        u64 mask[TOPK][8];  // 32000 B (phase-disjoint with SMemA)
    } u;
    float4 sbox[TOPK];      // 8000 B
    float  sscore[TOPK];    // 2000 B
    float  sarea[TOPK];     // 2000 B
    int    order[TOPK];     // 2000 B
    u64    rowflag[8];      // 64 B  (row i has any suppression bit)
    int    cand_count;
    int    bstar;
    int    n_emit;
};

// ---- mask + transpose odm_conf into per-task contiguous score arrays ----
__global__ __launch_bounds__(256)
void mask_transpose(const float* __restrict__ arm_conf,
                    const float* __restrict__ odm_conf,
                    float* __restrict__ ws) {
    __shared__ float tile[NCLS][CHUNK + 1];
    __shared__ float obj[CHUNK];
    const int blk = blockIdx.x;
    const int b = blk >> 6;
    const int ch = blk & 63;
    const int p0 = ch * CHUNK;
    const int np = min(CHUNK, P_NUM - p0);
    const int tid = threadIdx.x;

    const float* oc = odm_conf + ((size_t)b * P_NUM + p0) * NCLS;
    const float* ac = arm_conf + ((size_t)b * P_NUM + p0) * 2;
    const int count = np * NCLS;
    for (int i = tid; i < count; i += 256) {
        float v = oc[i];
        int p = i / NCLS;
        int c = i - p * NCLS;
        tile[c][p] = v;
    }
    if (tid < np) obj[tid] = ac[tid * 2 + 1];
    __syncthreads();

    for (int c = 1; c < NCLS; ++c) {
        float* w = ws + ((size_t)(b * 20 + (c - 1))) * P_NUM + p0;
        for (int p = tid; p < np; p += 256)
            w[p] = (obj[p] > OBJ_THR) ? tile[c][p] : 0.0f;
    }
}

template <bool PACKED>
__global__ __launch_bounds__(NTHREADS)
void refinedet_main(const float* __restrict__ arm_loc,
                    const float* __restrict__ arm_conf,
                    const float* __restrict__ odm_loc,
                    const float* __restrict__ odm_conf,
                    const float* __restrict__ priors,
                    const float* __restrict__ ws_scores,
                    float* __restrict__ out) {
    __shared__ SMem sm;
    const int task = blockIdx.x;
    const int tid = threadIdx.x;

    // ---- extra blocks: zero the class-0 slabs, then exit ----
    if (task >= NTASK) {
        float* o = out + (size_t)(task - NTASK) * NCLS * TOPK * 5;
        for (int f = tid; f < TOPK * 5; f += NTHREADS) o[f] = 0.0f;
        return;
    }

    const int b = task / (NCLS - 1);
    const int c = task % (NCLS - 1) + 1;

    // ---- Phase 0: load my 32 scores into registers (single global pass) ----
    float s[32];
    if (PACKED) {
        const float4* sp = (const float4*)(ws_scores + (size_t)task * P_NUM);
        #pragma unroll
        for (int v = 0; v < 8; ++v) {
            int q = tid + 512 * v;            // 4080 float4s total
            float4 val = (q < 4080) ? sp[q] : make_float4(0.f, 0.f, 0.f, 0.f);
            s[4 * v + 0] = val.x; s[4 * v + 1] = val.y;
            s[4 * v + 2] = val.z; s[4 * v + 3] = val.w;
        }
    } else {
        const float* armc = arm_conf + (size_t)b * P_NUM * 2;
        const float* odmc = odm_conf + (size_t)b * P_NUM * NCLS;
        #pragma unroll 4
        for (int k = 0; k < 32; ++k) {
            int p = tid + 512 * k;
            float sc = 0.0f;
            if (p < P_NUM) {
                float o = armc[p * 2 + 1];
                sc = (o > OBJ_THR) ? odmc[p * NCLS + c] : 0.0f;
            }
            s[k] = sc;
        }
    }
    for (int i = tid; i < NBUCKET; i += NTHREADS) sm.u.a.hist[i] = 0u;
    if (tid == 0) sm.cand_count = 0;
    __syncthreads();

    // ---- Phase 1: histogram from registers ----
    #pragma unroll 4
    for (int k = 0; k < 32; ++k) {
        float sc = s[k];
        if (sc > CONF_THR) {
            int bk = (int)(sc * (float)NBUCKET);
            if (bk > NBUCKET - 1) bk = NBUCKET - 1;
            atomicAdd(&sm.u.a.hist[bk], 1u);
        }
    }
    __syncthreads();

    // ---- Phase 2: threshold bucket b* (two-level scan) ----
    {
        int s4 = 0;
        #pragma unroll
        for (int q = 0; q < 4; ++q) s4 += (int)sm.u.a.hist[tid * 4 + q];
        sm.u.a.csum[tid] = s4;
    }
    __syncthreads();
    if (tid < 64) {
        int g = 0;
        #pragma unroll
        for (int q = 0; q < 8; ++q) g += sm.u.a.csum[tid * 8 + q];
        sm.u.a.gsum[tid] = g;
    }
    __syncthreads();
    if (tid == 0) {
        int cum = 0, bstar = 0;
        for (int gg = 63; gg >= 0; --gg) {
            int gs = sm.u.a.gsum[gg];
            if (cum + gs >= TOPK) {
                for (int t = gg * 8 + 7; t >= gg * 8; --t) {
                    int cs = sm.u.a.csum[t];
                    if (cum + cs >= TOPK) {
                        for (int bk = t * 4 + 3; bk >= t * 4; --bk) {
                            cum += (int)sm.u.a.hist[bk];
                            if (cum >= TOPK) { bstar = bk; goto found; }
                        }
                    }
                    cum += cs;
                }
            }
            cum += gs;
        }
found:
        sm.bstar = bstar;   // total < 500 -> stays 0 -> gather all valid
    }
    __syncthreads();
    const int bstar = sm.bstar;

    // ---- Phase 3: gather candidates from registers ----
    #pragma unroll 4
    for (int k = 0; k < 32; ++k) {
        float sc = s[k];
        if (sc > CONF_THR) {
            int bk = (int)(sc * (float)NBUCKET);
            if (bk > NBUCKET - 1) bk = NBUCKET - 1;
            if (bk >= bstar) {
                int p;
                if (PACKED) p = 4 * (tid + 512 * (k >> 2)) + (k & 3);
                else        p = tid + 512 * k;
                int pos = atomicAdd(&sm.cand_count, 1);
                if (pos < CAND_CAP) {
                    u64 key = ((u64)__float_as_uint(sc) << 32) | (u32)(~(u32)p);
                    sm.u.a.keys[pos] = key;
                }
            }
        }
    }
    __syncthreads();
    int M = sm.cand_count; if (M > CAND_CAP) M = CAND_CAP;
    const int S = (M <= 512) ? 512 : CAND_CAP;   // common case: M ~ 505
    for (int i = M + tid; i < S; i += NTHREADS) sm.u.a.keys[i] = 0ull;
    __syncthreads();

    // ---- Phase 4: bitonic sort S keys, descending ----
    for (int k = 2; k <= S; k <<= 1) {
        for (int j = k >> 1; j > 0; j >>= 1) {
            for (int t = tid; t < S; t += NTHREADS) {
                int ixj = t ^ j;
                if (ixj > t) {
                    u64 a = sm.u.a.keys[t];
                    u64 bb = sm.u.a.keys[ixj];
                    bool desc = ((t & k) == 0);
                    if (desc ? (a < bb) : (a > bb)) {
                        sm.u.a.keys[t] = bb;
                        sm.u.a.keys[ixj] = a;
                    }
                }
            }
            __syncthreads();
        }
    }
    const int N = (M < TOPK) ? M : TOPK;

    // ---- Phase 5: cascaded decode for top-N (exact ref FP: no FMA, CR exp) ----
    if (tid < 8) sm.rowflag[tid] = 0ull;
    for (int i = tid; i < TOPK; i += NTHREADS) {
        if (i < N) {
            u64 key = sm.u.a.keys[i];
            float sc = __uint_as_float((u32)(key >> 32));
            int p = (int)(~(u32)(key & 0xFFFFFFFFull));
            float4 pr = ((const float4*)priors)[p];
            float4 al = ((const float4*)(arm_loc + (size_t)b * P_NUM * 4))[p];
            float4 ol = ((const float4*)(odm_loc + (size_t)b * P_NUM * 4))[p];
            float cx = __fadd_rn(pr.x, __fmul_rn(__fmul_rn(al.x, 0.1f), pr.z));
            float cy = __fadd_rn(pr.y, __fmul_rn(__fmul_rn(al.y, 0.1f), pr.w));
            float w  = __fmul_rn(pr.z, (float)exp((double)__fmul_rn(al.z, 0.2f)));
            float h  = __fmul_rn(pr.w, (float)exp((double)__fmul_rn(al.w, 0.2f)));
            float mnx = __fsub_rn(cx, __fmul_rn(w, 0.5f));
            float mny = __fsub_rn(cy, __fmul_rn(h, 0.5f));
            float mxx = __fadd_rn(mnx, w);
            float mxy = __fadd_rn(mny, h);
            float dcx = __fmul_rn(__fadd_rn(mxx, mnx), 0.5f);
            float dcy = __fmul_rn(__fadd_rn(mxy, mny), 0.5f);
            float dw  = __fsub_rn(mxx, mnx);
            float dh  = __fsub_rn(mxy, mny);
            float cx2 = __fadd_rn(dcx, __fmul_rn(__fmul_rn(ol.x, 0.1f), dw));
            float cy2 = __fadd_rn(dcy, __fmul_rn(__fmul_rn(ol.y, 0.1f), dh));
            float w2  = __fmul_rn(dw, (float)exp((double)__fmul_rn(ol.z, 0.2f)));
            float h2  = __fmul_rn(dh, (float)exp((double)__fmul_rn(ol.w, 0.2f)));
            float x1 = __fsub_rn(cx2, __fmul_rn(w2, 0.5f));
            float y1 = __fsub_rn(cy2, __fmul_rn(h2, 0.5f));
            float x2 = __fadd_rn(x1, w2);
            float y2 = __fadd_rn(y1, h2);
            sm.sbox[i] = make_float4(x1, y1, x2, y2);
            sm.sscore[i] = sc;
            sm.sarea[i] = __fmul_rn(__fsub_rn(x2, x1), __fsub_rn(y2, y1));
        } else {
            sm.sbox[i] = make_float4(0.f, 0.f, 0.f, 0.f);
            sm.sscore[i] = 0.0f;
            sm.sarea[i] = 0.0f;
        }
    }
    __syncthreads();   // keys (union) dead; mask region live; rowflag zeroed

    // ---- Phase 6: triangular suppression bitmask (j > i), fast-rcp IoU ----
    // Exact decisions: v_rcp error ~1e-7; only |q-0.45|<1e-3 falls back to
    // the exact __fdiv_rn path (rare). NaN (0/0) -> no suppress, both paths.
    {
        auto do_row = [&](int i) {
            float4 bi = sm.sbox[i];
            float ai = sm.sarea[i];
            u64 any = 0ull;
            #pragma unroll
            for (int w = 0; w < 8; ++w) {
                if (w < (i >> 6)) continue;        // triangular: words >= i/64
                int jlo = max(i + 1, w * 64);
                int jhi = min(N, (w + 1) * 64);
                u64 bits = 0ull;
                for (int j = jlo; j < jhi; ++j) {
                    float4 bj = sm.sbox[j];
                    float xx1 = fmaxf(bj.x, bi.x);
                    float yy1 = fmaxf(bj.y, bi.y);
                    float xx2 = fminf(bj.z, bi.z);
                    float yy2 = fminf(bj.w, bi.w);
                    float iw = fmaxf(__fsub_rn(xx2, xx1), 0.0f);
                    float ih = fmaxf(__fsub_rn(yy2, yy1), 0.0f);
                    float inter = __fmul_rn(iw, ih);
                    float denom = __fadd_rn(__fsub_rn(sm.sarea[j], inter), ai);
                    float q = __fmul_rn(inter, __builtin_amdgcn_rcpf(denom));
                    bool sup;
                    if (__builtin_expect(fabsf(__fsub_rn(q, NMS_THR)) < 1e-3f, 0))
                        sup = __fdiv_rn(inter, denom) > NMS_THR;
                    else
                        sup = q > NMS_THR;
                    if (sup) bits |= (1ull << (j & 63));
                }
                sm.u.mask[i][w] = bits;
                any |= bits;
            }
            if (any) atomicOr(&sm.rowflag[i >> 6], 1ull << (i & 63));
        };
        if (tid < TOPK / 2) {
            int r0 = tid, r1 = TOPK - 1 - tid;
            if (r0 < N) do_row(r0);
            if (r1 < N) do_row(r1);
        }
    }
    __syncthreads();

    // ---- Phase 7: serial greedy sweep, flag-gated (static reg indices) ----
    if (tid == 0) {
        u64 cur[8], fl[8];
        #pragma unroll
        for (int w = 0; w < 8; ++w) {
            int lo = w * 64;
            u64 m;
            if (N >= lo + 64)      m = ~0ull;
            else if (N <= lo)      m = 0ull;
            else                   m = (1ull << (N - lo)) - 1ull;
            cur[w] = m;
            fl[w] = sm.rowflag[w];
        }
        int cnt = 0;
        #pragma unroll
        for (int w = 0; w < 8; ++w) {
            u64 a = cur[w];
            while (a) {
                int bpos = __ffsll((unsigned long long)a) - 1;
                a &= a - 1;                    // clear lowest set bit (= bpos)
                int i = w * 64 + bpos;
                sm.order[cnt++] = i;
                if ((fl[w] >> bpos) & 1ull) {  // row i suppresses something
                    a &= ~sm.u.mask[i][w];
                    #pragma unroll
                    for (int ww = w + 1; ww < 8; ++ww)
                        cur[ww] &= ~sm.u.mask[i][ww];
                }
            }
        }
        sm.n_emit = cnt;
    }
    __syncthreads();

    // ---- Phase 8: write full [500,5] slab (zeros beyond cnt) ----
    float* o = out + ((size_t)(b * NCLS + c)) * TOPK * 5;
    const int cnt = sm.n_emit;
    for (int f = tid; f < TOPK * 5; f += NTHREADS) {
        int k = f / 5;
        int r = f - k * 5;
        float val = 0.0f;
        if (k < cnt) {
            int i = sm.order[k];
            float4 bx = sm.sbox[i];
            val = (r == 0) ? sm.sscore[i]
                : (r == 1) ? bx.x
                : (r == 2) ? bx.y
                : (r == 3) ? bx.z
                :            bx.w;
        }
        o[f] = val;
    }
}

extern "C" void kernel_launch(void* const* d_in, const int* in_sizes, int n_in,
                              void* d_out, int out_size, void* d_ws, size_t ws_size,
                              hipStream_t stream) {
    const float* arm_loc  = (const float*)d_in[0];
    const float* arm_conf = (const float*)d_in[1];
    const float* odm_loc  = (const float*)d_in[2];
    const float* odm_conf = (const float*)d_in[3];
    const float* priors   = (const float*)d_in[4];
    float* out = (float*)d_out;

    const int grid = NTASK + B_NUM;   // 640 tasks + 32 class-0 zeroers
    const size_t need = (size_t)NTASK * P_NUM * sizeof(float); // 41.8 MB
    if (ws_size >= need) {
        float* wsf = (float*)d_ws;
        mask_transpose<<<B_NUM * 64, 256, 0, stream>>>(arm_conf, odm_conf, wsf);
        refinedet_main<true><<<grid, NTHREADS, 0, stream>>>(
            arm_loc, arm_conf, odm_loc, odm_conf, priors, wsf, out);
    } else {
        refinedet_main<false><<<grid, NTHREADS, 0, stream>>>(
            arm_loc, arm_conf, odm_loc, odm_conf, priors, nullptr, out);
    }
}